// Round 10
// baseline (133.461 us; speedup 1.0000x reference)
//
#include <hip/hip_runtime.h>
#include <math.h>

#define N_NODES 1024
#define N_EVAL 131072
#define NUM_POLES 8
#define PI_D 3.14159265358979323846

// ws layout: float4 pk[1024] = (node, w, w*v, 0).
//
// Closed-form barycentric weights for Chebyshev points of the 2nd kind
// x_j = cos(pi*j/n), n = N_NODES-1:
//   1/prod_{i!=j}(x_j-x_i) = (-1)^j * delta_j * 2^(n-1)/n, delta=1/2 at ends.
// Uniform positive scalings cancel in num/den, so:
//   w_j = (-1)^j * delta_j * prod_m((x_j-pr_m)^2 + pi_m^2)
// Kept OUT of the hot kernel: f64 register pressure inside the eval kernel
// is what forced R8's 50 MB spill under the 64-VGPR/8-wave cap.
__global__ void wk_setup(const float* __restrict__ values,
                         const float* __restrict__ poles_real,
                         const float* __restrict__ poles_imag,
                         float4* __restrict__ pk) {
    const int j = blockIdx.x * 128 + threadIdx.x;
    const double nd = cos(PI_D * (double)j / (double)(N_NODES - 1));
    double prod = (j == 0 || j == N_NODES - 1) ? 0.5 : 1.0;
#pragma unroll
    for (int m = 0; m < NUM_POLES; ++m) {
        const double dr = nd - (double)poles_real[m];
        const double di = (double)poles_imag[m];
        prod *= dr * dr + di * di;
    }
    if (j & 1) prod = -prod;
    pk[j] = make_float4((float)nd, (float)prod,
                        (float)(prod * (double)values[j]), 0.0f);
}

// Hot kernel: pure f32. Block = 512 threads = 8 waves; 128 points/block
// (2 per lane); wave w covers node chunk [128w,128w+128) for all 128
// block-points. Grid 1024 blocks = 4 blocks/CU = 32 waves/CU = 8 waves/SIMD
// (VGPR ~32 <= 64 with the f64 phase gone -> no cap, no spill; this is the
// first round combining max occupancy + P=2 LDS amortization + clean f32).
// Plain v_rcp_f32 (no Newton; absmax 0.0156 validated R2/R3/R6). Exact node
// hits (d==0) poison accumulators with inf/NaN -> rare global-scan fix-up
// (reference: exact-hit column reduces to sum(hit wv)/sum(hit w)).
__global__ __launch_bounds__(512) void eval_kernel(
    const float* __restrict__ x_eval,
    const float4* __restrict__ pk,
    float* __restrict__ out) {
    __shared__ __align__(16) float s_n[N_NODES];
    __shared__ __align__(16) float s_w[N_NODES];
    __shared__ __align__(16) float s_v[N_NODES];
    __shared__ float2 s_r[8][128];

    const int t = threadIdx.x;

    // Stage node table (coalesced float4 reads, 2 nodes/thread).
#pragma unroll
    for (int h = 0; h < 2; ++h) {
        const int j = t + h * 512;
        const float4 e = pk[j];
        s_n[j] = e.x;
        s_w[j] = e.y;
        s_v[j] = e.z;
    }
    __syncthreads();

    const int lane = t & 63;
    const int wid  = t >> 6;  // 0..7 -> node chunk
    const int pbase = blockIdx.x * 128;
    const float x0 = x_eval[pbase + lane];
    const float x1 = x_eval[pbase + 64 + lane];

    const float4* n4 = (const float4*)s_n + wid * 32;
    const float4* w4 = (const float4*)s_w + wid * 32;
    const float4* v4 = (const float4*)s_v + wid * 32;

    float a0 = 0.0f, b0 = 0.0f;  // num/den for x0
    float a1 = 0.0f, b1 = 0.0f;  // num/den for x1

#define NODE(C)                                                            \
    {                                                                      \
        const float d0 = x0 - an.C;                                        \
        const float d1 = x1 - an.C;                                        \
        const float r0 = __builtin_amdgcn_rcpf(d0);                        \
        const float r1 = __builtin_amdgcn_rcpf(d1);                        \
        a0 = fmaf(av.C, r0, a0); b0 = fmaf(aw.C, r0, b0);                  \
        a1 = fmaf(av.C, r1, a1); b1 = fmaf(aw.C, r1, b1);                  \
    }

#pragma unroll 4
    for (int q = 0; q < 32; ++q) {
        const float4 an = n4[q];
        const float4 aw = w4[q];
        const float4 av = v4[q];
        NODE(x) NODE(y) NODE(z) NODE(w)
    }
#undef NODE

    s_r[wid][lane]      = make_float2(a0, b0);
    s_r[wid][lane + 64] = make_float2(a1, b1);
    __syncthreads();

    if (t < 128) {
        float nn = 0.0f, dd = 0.0f;
#pragma unroll
        for (int w = 0; w < 8; ++w) {
            const float2 pr = s_r[w][t];
            nn += pr.x;
            dd += pr.y;
        }
        float res = nn / dd;
        if (__builtin_expect(__builtin_isnan(res), 0)) {
            const float x = x_eval[pbase + t];
            float hn = 0.0f, hd = 0.0f;
            for (int j = 0; j < N_NODES; ++j) {
                const float4 e = pk[j];
                if (e.x == x) { hn += e.z; hd += e.y; }
            }
            res = hn / hd;
        }
        out[pbase + t] = res;
    }
}

extern "C" void kernel_launch(void* const* d_in, const int* in_sizes, int n_in,
                              void* d_out, int out_size, void* d_ws, size_t ws_size,
                              hipStream_t stream) {
    const float* x_eval     = (const float*)d_in[0];
    const float* values     = (const float*)d_in[1];
    const float* poles_real = (const float*)d_in[2];
    const float* poles_imag = (const float*)d_in[3];
    float* out = (float*)d_out;

    float4* pk = (float4*)d_ws;

    wk_setup<<<8, 128, 0, stream>>>(values, poles_real, poles_imag, pk);
    eval_kernel<<<N_EVAL / 128, 512, 0, stream>>>(x_eval, pk, out);
}

// Round 11
// 131.696 us; speedup vs baseline: 1.0134x; 1.0134x over previous
//
#include <hip/hip_runtime.h>
#include <math.h>

#define N_NODES 1024
#define N_EVAL 131072
#define NUM_POLES 8
#define PI_D 3.14159265358979323846

// ws layout: float4 pk[1024] = (node, w, w*v, 0).
//
// Closed-form barycentric weights for Chebyshev points of the 2nd kind
// x_j = cos(pi*j/n), n = N_NODES-1:
//   1/prod_{i!=j}(x_j-x_i) = (-1)^j * delta_j * 2^(n-1)/n, delta=1/2 at ends.
// Uniform positive scalings cancel in num/den, so:
//   w_j = (-1)^j * delta_j * prod_m((x_j-pr_m)^2 + pi_m^2)
// Kept out of the hot kernel (f64 pressure caused R8's 50 MB spill).
__global__ void wk_setup(const float* __restrict__ values,
                         const float* __restrict__ poles_real,
                         const float* __restrict__ poles_imag,
                         float4* __restrict__ pk) {
    const int j = blockIdx.x * 128 + threadIdx.x;
    const double nd = cos(PI_D * (double)j / (double)(N_NODES - 1));
    double prod = (j == 0 || j == N_NODES - 1) ? 0.5 : 1.0;
#pragma unroll
    for (int m = 0; m < NUM_POLES; ++m) {
        const double dr = nd - (double)poles_real[m];
        const double di = (double)poles_imag[m];
        prod *= dr * dr + di * di;
    }
    if (j & 1) prod = -prod;
    pk[j] = make_float4((float)nd, (float)prod,
                        (float)(prod * (double)values[j]), 0.0f);
}

// Hot kernel. Block = 1024 threads = 16 waves; 256 points/block (P=4 per
// lane); wave w covers node chunk [64w, 64w+64) for all 256 block-points
// (waves read DIFFERENT chunks -> naturally de-phased on the LDS pipe).
// Grid 512 blocks = 2 blocks/CU = 32 waves/CU = 8 waves/SIMD.
// Batch-2 reciprocal: r = rcp(dA*dB); 1/dA = r*dB; 1/dB = r*dA — 9 VALU +
// 1 trans per 2 node-point pairs (halves trans-pipe pressure vs plain rcp).
// Exact node hits (d==0) make r = rcp(0 * d') = inf (or rcp(0)) -> fma
// poisons accumulators with inf/NaN -> rare global-scan fix-up (reference:
// exact-hit column reduces to sum(hit wv)/sum(hit w)). absmax 0.0156
// validated across R2..R10 for both plain and batch-2 forms.
__global__ __launch_bounds__(1024, 8) void eval_kernel(
    const float* __restrict__ x_eval,
    const float4* __restrict__ pk,
    float* __restrict__ out) {
    __shared__ __align__(16) float s_n[N_NODES];
    __shared__ __align__(16) float s_w[N_NODES];
    __shared__ __align__(16) float s_v[N_NODES];
    __shared__ float2 s_r[16][256];  // 32 KB partials

    const int t = threadIdx.x;

    // Stage node table (coalesced float4, 1 node/thread).
    {
        const float4 e = pk[t];
        s_n[t] = e.x;
        s_w[t] = e.y;
        s_v[t] = e.z;
    }
    __syncthreads();

    const int lane = t & 63;
    const int wid  = t >> 6;  // 0..15 -> 64-node chunk
    const int pbase = blockIdx.x * 256;
    const float x0 = x_eval[pbase + lane];
    const float x1 = x_eval[pbase + 64 + lane];
    const float x2 = x_eval[pbase + 128 + lane];
    const float x3 = x_eval[pbase + 192 + lane];

    const float4* n4 = (const float4*)s_n + wid * 16;
    const float4* w4 = (const float4*)s_w + wid * 16;
    const float4* v4 = (const float4*)s_v + wid * 16;

    float a0 = 0.0f, b0 = 0.0f, a1 = 0.0f, b1 = 0.0f;
    float a2 = 0.0f, b2 = 0.0f, a3 = 0.0f, b3 = 0.0f;

    // One node-PAIR (nA,nB) for all 4 points with a single rcp per point.
#define PAIR(nA, wA, vA, nB, wB, vB)                                       \
    {                                                                      \
        const float dA0 = x0 - (nA), dB0 = x1 - (nA);                      \
        const float dA1 = x2 - (nA), dB1 = x3 - (nA);                      \
        const float eA0 = x0 - (nB), eB0 = x1 - (nB);                      \
        const float eA1 = x2 - (nB), eB1 = x3 - (nB);                      \
        const float r0 = __builtin_amdgcn_rcpf(dA0 * eA0);                 \
        const float r1 = __builtin_amdgcn_rcpf(dB0 * eB0);                 \
        const float r2 = __builtin_amdgcn_rcpf(dA1 * eA1);                 \
        const float r3 = __builtin_amdgcn_rcpf(dB1 * eB1);                 \
        const float iA0 = r0 * eA0, iB0 = r0 * dA0;                        \
        const float iA1 = r1 * eB0, iB1 = r1 * dB0;                        \
        const float iA2 = r2 * eA1, iB2 = r2 * dA1;                        \
        const float iA3 = r3 * eB1, iB3 = r3 * dB1;                        \
        a0 = fmaf((vA), iA0, a0); b0 = fmaf((wA), iA0, b0);                \
        a0 = fmaf((vB), iB0, a0); b0 = fmaf((wB), iB0, b0);                \
        a1 = fmaf((vA), iA1, a1); b1 = fmaf((wA), iA1, b1);                \
        a1 = fmaf((vB), iB1, a1); b1 = fmaf((wB), iB1, b1);                \
        a2 = fmaf((vA), iA2, a2); b2 = fmaf((wA), iA2, b2);                \
        a2 = fmaf((vB), iB2, a2); b2 = fmaf((wB), iB2, b2);                \
        a3 = fmaf((vA), iA3, a3); b3 = fmaf((wA), iA3, b3);                \
        a3 = fmaf((vB), iB3, a3); b3 = fmaf((wB), iB3, b3);                \
    }

#pragma unroll 2
    for (int q = 0; q < 16; ++q) {
        const float4 an = n4[q];
        const float4 aw = w4[q];
        const float4 av = v4[q];
        PAIR(an.x, aw.x, av.x, an.y, aw.y, av.y)
        PAIR(an.z, aw.z, av.z, an.w, aw.w, av.w)
    }
#undef PAIR

    s_r[wid][lane]       = make_float2(a0, b0);
    s_r[wid][lane + 64]  = make_float2(a1, b1);
    s_r[wid][lane + 128] = make_float2(a2, b2);
    s_r[wid][lane + 192] = make_float2(a3, b3);
    __syncthreads();

    if (t < 256) {
        float nn = 0.0f, dd = 0.0f;
#pragma unroll
        for (int w = 0; w < 16; ++w) {
            const float2 pr = s_r[w][t];
            nn += pr.x;
            dd += pr.y;
        }
        float res = nn / dd;
        if (__builtin_expect(__builtin_isnan(res) | __builtin_isinf(res), 0)) {
            const float x = x_eval[pbase + t];
            float hn = 0.0f, hd = 0.0f;
            for (int j = 0; j < N_NODES; ++j) {
                const float4 e = pk[j];
                if (e.x == x) { hn += e.z; hd += e.y; }
            }
            res = hn / hd;
        }
        out[pbase + t] = res;
    }
}

extern "C" void kernel_launch(void* const* d_in, const int* in_sizes, int n_in,
                              void* d_out, int out_size, void* d_ws, size_t ws_size,
                              hipStream_t stream) {
    const float* x_eval     = (const float*)d_in[0];
    const float* values     = (const float*)d_in[1];
    const float* poles_real = (const float*)d_in[2];
    const float* poles_imag = (const float*)d_in[3];
    float* out = (float*)d_out;

    float4* pk = (float4*)d_ws;

    wk_setup<<<8, 128, 0, stream>>>(values, poles_real, poles_imag, pk);
    eval_kernel<<<N_EVAL / 256, 1024, 0, stream>>>(x_eval, pk, out);
}